// Round 14
// baseline (47.153 us; speedup 1.0000x reference)
//
#include <hip/hip_runtime.h>

#define NN 10000    // nodes
#define NE 25000    // edges
#define DF 128      // features
#define SB 256      // block size
#define NBLK ((NE + SB - 1) / SB)          // 98 scan blocks
#define NEWXB ((NE * 32 + SB - 1) / SB)    // 3125 newx blocks

typedef float f4 __attribute__((ext_vector_type(4)));   // native vec for NT stores

// ---------------------------------------------------------------------------
// K1: new_x[e] = ((x[u]+x[v])*0.5 + ea[e])*0.5 (32 thr/edge, float4)
//     + init head[]=-1 and lookback flags=0.  (R6 structure, unchanged.)
// ---------------------------------------------------------------------------
__global__ void k_newx_init(const float* __restrict__ x, const float* __restrict__ ea,
                            const int* __restrict__ c0, const int* __restrict__ c1,
                            float* __restrict__ out, int* __restrict__ head,
                            int* __restrict__ gFlag) {
    int tid = blockIdx.x * blockDim.x + threadIdx.x;
    if (tid < NN) head[tid] = -1;
    if (tid < NBLK) gFlag[tid] = 0;
    if (tid >= NE * 32) return;
    int e = tid >> 5, q = tid & 31;
    int u = c0[e], v = c1[e];
    float4 a  = ((const float4*)(x + (size_t)u * DF))[q];
    float4 bb = ((const float4*)(x + (size_t)v * DF))[q];
    float4 c  = ((const float4*)(ea + (size_t)e * DF))[q];
    float4 r;
    r.x = ((a.x + bb.x) * 0.5f + c.x) * 0.5f;
    r.y = ((a.y + bb.y) * 0.5f + c.y) * 0.5f;
    r.z = ((a.z + bb.z) * 0.5f + c.z) * 0.5f;
    r.w = ((a.w + bb.w) * 0.5f + c.w) * 0.5f;
    ((float4*)(out + (size_t)e * DF))[q] = r;
}

// ---------------------------------------------------------------------------
// K2: per-node linked lists in one pass. Kernel boundary = cheap coherence
// point (R9/R11/R12 lesson: intra-kernel producer->consumer handoff loses).
// ---------------------------------------------------------------------------
__global__ void k_link(const int* __restrict__ c0,
                       int* __restrict__ head, int* __restrict__ nxt) {
    int j = blockIdx.x * blockDim.x + threadIdx.x;
    if (j >= NE) return;
    nxt[j] = atomicExch(&head[c0[j]], j);
}

// ---------------------------------------------------------------------------
// K3: fused cnt + 98-block lookback scan + index emission.
// Per-thread: count walk -> LDS scan -> lookback -> base. Then a second
// (L1/L2-hot) walk writes ALL small outputs directly:
//   rows[base+t]  = i      (every entry of segment i equals i -> no ranking)
//   cols[base+rk] = j      (rank-by-value restores ascending-j order)
//   attrSrc[base+t] = v    (gather index for K4)
// rowStart never materializes; K4 has zero list work left.
// ---------------------------------------------------------------------------
__global__ __launch_bounds__(SB) void k_scan_idx(const int* __restrict__ c0,
                                                 const int* __restrict__ c1,
                                                 const int* __restrict__ head,
                                                 const int* __restrict__ nxt,
                                                 int* __restrict__ gFlag,
                                                 float* __restrict__ outRows,
                                                 float* __restrict__ outCols,
                                                 int* __restrict__ attrSrc) {
    __shared__ int sc[SB];
    __shared__ int sr[SB];
    int b = blockIdx.x, t = threadIdx.x;
    int i = b * SB + t;
    int u = 0, v = 0, cnt = 0;
    if (i < NE) {
        u = c0[i]; v = c1[i];
        for (int j = head[v]; j != -1; j = nxt[j])
            if (c1[j] != u) ++cnt;
    }
    sc[t] = cnt;
    __syncthreads();
    for (int off = 1; off < SB; off <<= 1) {
        int add = (t >= off) ? sc[t - off] : 0;
        __syncthreads();
        sc[t] += add;
        __syncthreads();
    }
    int blockSum = sc[SB - 1];
    if (t == 0) atomicExch(&gFlag[b], blockSum + 1);   // publish
    int val = 0;
    if (t < b) {                                       // parallel lookback
        int v2;
        do { v2 = atomicAdd(&gFlag[t], 0); } while (v2 == 0);
        val = v2 - 1;
    }
    sr[t] = val;
    __syncthreads();
    for (int off = SB / 2; off > 0; off >>= 1) {
        if (t < off) sr[t] += sr[t + off];
        __syncthreads();
    }
    int base = sr[0] + sc[t] - cnt;                    // exclusive prefix of edge i

    if (i < NE && cnt > 0) {
        float fi = (float)i;
        for (int t2 = 0; t2 < cnt; ++t2) {
            __builtin_nontemporal_store(fi, &outRows[base + t2]);
            attrSrc[base + t2] = v;
        }
        // cols with rank-by-value (second walk is L1/L2-hot after count walk)
        for (int j = head[v]; j != -1; j = nxt[j]) {
            if (c1[j] == u) continue;
            int rank = 0;
            for (int j2 = head[v]; j2 != -1; j2 = nxt[j2])
                rank += (c1[j2] != u && j2 < j) ? 1 : 0;
            __builtin_nontemporal_store((float)j, &outCols[base + rank]);
        }
    }
}

// ---------------------------------------------------------------------------
// K4: pure-BW gather. Wave w copies output rows 2w (lanes 0-31) and 2w+1
// (lanes 32-63): attr[k] = newx[attrSrc[k]]; f4/lane -> 1KB per store, NT.
// No list walks, no divergence, perfectly balanced over E_lg.
// ---------------------------------------------------------------------------
__global__ void k_gather(const float* __restrict__ newx,
                         const int* __restrict__ attrSrc,
                         float* __restrict__ outAttr, int elg) {
    int gtid = blockIdx.x * blockDim.x + threadIdx.x;
    int w = gtid >> 6, lane = gtid & 63;
    int k = 2 * w + (lane >> 5);
    if (k >= elg) return;
    int src = attrSrc[k];
    int q = lane & 31;
    f4 val = ((const f4*)(newx + (size_t)src * DF))[q];
    __builtin_nontemporal_store(val, &((f4*)(outAttr + (size_t)k * DF))[q]);
}

// ---------------------------------------------------------------------------

extern "C" void kernel_launch(void* const* d_in, const int* in_sizes, int n_in,
                              void* d_out, int out_size, void* d_ws, size_t ws_size,
                              hipStream_t stream) {
    const float* x  = (const float*)d_in[0];
    const float* ea = (const float*)d_in[1];
    const int*   ei = (const int*)d_in[2];
    const int* c0 = ei;        // edge_index[0]
    const int* c1 = ei + NE;   // edge_index[1]

    float* out = (float*)d_out;
    int E_lg = (out_size - NE * DF) / (DF + 2);
    if (E_lg < 0) E_lg = 0;

    float* out_newx = out;                      // NE*DF
    float* out_rows = out + (size_t)NE * DF;    // E_lg
    float* out_cols = out_rows + E_lg;          // E_lg
    float* out_attr = out_cols + E_lg;          // E_lg*DF

    int* ws      = (int*)d_ws;
    int* head    = ws;                          // NN
    int* nxt     = head + NN;                   // NE
    int* gFlag   = nxt + NE;                    // NBLK
    int* attrSrc = gFlag + NBLK;                // E_lg

    k_newx_init<<<NEWXB, SB, 0, stream>>>(x, ea, c0, c1, out_newx, head, gFlag);
    k_link<<<(NE + SB - 1) / SB, SB, 0, stream>>>(c0, head, nxt);
    k_scan_idx<<<NBLK, SB, 0, stream>>>(c0, c1, head, nxt, gFlag,
                                        out_rows, out_cols, attrSrc);
    if (E_lg > 0) {
        int waves = (E_lg + 1) / 2;
        int blocks = (waves * 64 + SB - 1) / SB;
        k_gather<<<blocks, SB, 0, stream>>>(out_newx, attrSrc, out_attr, E_lg);
    }
}